// Round 1
// 434.092 us; speedup vs baseline: 1.1533x; 1.1533x over previous
//
#include <hip/hip_runtime.h>

#define B_ 4
#define N_ 4096
#define D_ 1024
#define R_ 32
#define BN_ (B_ * N_)

typedef __attribute__((ext_vector_type(8))) short short8;
typedef __attribute__((ext_vector_type(4))) float f32x4;

// round-to-nearest-even fp32 -> bf16
__device__ inline unsigned int f2bf(float f) {
  unsigned int u = __float_as_uint(f);
  return (u + 0x7fffu + ((u >> 16) & 1u)) >> 16;
}

// packed RNE fp32x2 -> bf16x2 in one VALU op (no builtin on gfx950; T12 recipe)
__device__ inline unsigned int cvt_pk_bf16(float lo, float hi) {
  unsigned int r;
  asm("v_cvt_pk_bf16_f32 %0, %1, %2" : "=v"(r) : "v"(lo), "v"(hi));
  return r;
}

// swap lanes 0<->1, 2<->3 (pairs ln^1) on the VALU pipe (DPP quad_perm [1,0,3,2])
__device__ inline float dpp_swap1(float x) {
  return __int_as_float(
      __builtin_amdgcn_mov_dpp(__float_as_int(x), 0xB1, 0xF, 0xF, true));
}

// ---------------------------------------------------------------------------
// Kernel 1 (NEW): u = (q @ Wu) * log2e/sqrt(R), vp = k @ Wv via split-bf16 MFMA.
//   x = xh + xl (two RNE bf16 halves), W likewise; u = xh*Wh + xh*Wl + xl*Wh
//   (dropped xl*Wl ~ 2^-18 — negligible vs the final bf16 rounding of u).
// HBM-bound (~134 MB reads). Replaces the LDS-issue-bound scalar-FMA version.
// grid (BN/64, 2), 256 thr (4 waves, wave w owns rowtile w = rows 16w..16w+15).
//
// A-frag LDS layout is frag-linear: region fr = rt*2+ks (rt=row>>4, ks=k>>5),
// inside a region: qd-group stride UV_GS, lane-linear 8 shorts each.
// Strides chosen so b128 reads and u32 staging writes are <=2-way bank aliased,
// and all b128 addresses stay 16B-aligned (UV_GS*2=272, UV_RS*2=1104, both %16==0).
// ---------------------------------------------------------------------------
#define UV_GS 136
#define UV_RS 552   // 4*UV_GS + 8

__global__ __launch_bounds__(256) void uv_mfma_kernel(
    const float* __restrict__ q, const float* __restrict__ kmat,
    const float* __restrict__ Wu, const float* __restrict__ Wv,
    unsigned short* __restrict__ u, unsigned short* __restrict__ vp)
{
  __shared__ unsigned short ah_lds[8 * UV_RS];   // hi A-frags, 8 regions
  __shared__ unsigned short al_lds[8 * UV_RS];   // lo A-frags
  __shared__ unsigned short wth[32][72];         // W^T hi  [col][k], pad 8
  __shared__ unsigned short wtl[32][72];         // W^T lo

  const int t = threadIdx.x;
  const float* __restrict__ x = (blockIdx.y == 0) ? q : kmat;
  const float* __restrict__ W = (blockIdx.y == 0) ? Wu : Wv;
  unsigned short* __restrict__ o = (blockIdx.y == 0) ? u : vp;
  // 1/sqrt(32) * log2(e): fold softmax scale + exp->exp2 conversion into u
  const float osc = (blockIdx.y == 0)
      ? (0.17677669529663687f * 1.4426950408889634f) : 1.0f;

  const int r0 = blockIdx.x * 64;
  const int lane = t & 63;
  const int w = t >> 6;        // wave id == rowtile rt
  const int qd = lane >> 4;
  const int ln = lane & 15;

  f32x4 acc[2];
#pragma unroll
  for (int ct = 0; ct < 2; ++ct)
#pragma unroll
    for (int i = 0; i < 4; ++i) acc[ct][i] = 0.f;

  const int a_rd = qd * UV_GS + ln * 8;  // per-lane offset inside a region

  for (int k0 = 0; k0 < D_; k0 += 64) {
    // ---- stage x tile (64 rows x 64 k f32), split to bf16 hi/lo A-frags ----
#pragma unroll
    for (int i = 0; i < 4; ++i) {
      int idx = t + i * 256;          // 0..1023
      int row = idx >> 4;             // 0..63
      int kc = (idx & 15) * 4;        // 0..60
      float4 f = *(const float4*)&x[(size_t)(r0 + row) * D_ + k0 + kc];
      int fr = (row >> 4) * 2 + (kc >> 5);
      int off = fr * UV_RS + ((kc >> 3) & 3) * UV_GS + (row & 15) * 8 + (kc & 7);
      unsigned int h01 = cvt_pk_bf16(f.x, f.y);
      unsigned int h23 = cvt_pk_bf16(f.z, f.w);
      float hx = __uint_as_float(h01 << 16);
      float hy = __uint_as_float(h01 & 0xffff0000u);
      float hz = __uint_as_float(h23 << 16);
      float hw = __uint_as_float(h23 & 0xffff0000u);
      unsigned int l01 = cvt_pk_bf16(f.x - hx, f.y - hy);
      unsigned int l23 = cvt_pk_bf16(f.z - hz, f.w - hw);
      *(unsigned int*)&ah_lds[off]     = h01;
      *(unsigned int*)&ah_lds[off + 2] = h23;
      *(unsigned int*)&al_lds[off]     = l01;
      *(unsigned int*)&al_lds[off + 2] = l23;
    }
    // ---- stage W chunk transposed: [k][32] f32 -> W^T hi/lo [col][k] bf16 ----
#pragma unroll
    for (int i = 0; i < 2; ++i) {
      int idx = t + i * 256;          // 0..511
      int kr = idx >> 3;              // 0..63
      int cc = (idx & 7) * 4;         // 0..28
      float4 fw = *(const float4*)&W[(size_t)(k0 + kr) * R_ + cc];
      float vv[4] = {fw.x, fw.y, fw.z, fw.w};
#pragma unroll
      for (int j = 0; j < 4; ++j) {
        unsigned int hb = f2bf(vv[j]);
        wth[cc + j][kr] = (unsigned short)hb;
        float lo = vv[j] - __uint_as_float(hb << 16);
        wtl[cc + j][kr] = (unsigned short)f2bf(lo);
      }
    }
    __syncthreads();

    // ---- B-frags (tiny W) to registers for this k-tile ----
    short8 bh[2][2], bl[2][2];        // [coltile][kstep]
#pragma unroll
    for (int ct = 0; ct < 2; ++ct)
#pragma unroll
      for (int ks = 0; ks < 2; ++ks) {
        bh[ct][ks] = *(const short8*)&wth[ct * 16 + ln][ks * 32 + qd * 8];
        bl[ct][ks] = *(const short8*)&wtl[ct * 16 + ln][ks * 32 + qd * 8];
      }

    // ---- MFMA: 2 ksteps x 2 coltiles x 3 split terms ----
#pragma unroll
    for (int ks = 0; ks < 2; ++ks) {
      short8 ah = *(const short8*)&ah_lds[(w * 2 + ks) * UV_RS + a_rd];
      short8 al = *(const short8*)&al_lds[(w * 2 + ks) * UV_RS + a_rd];
#pragma unroll
      for (int ct = 0; ct < 2; ++ct) {
        acc[ct] = __builtin_amdgcn_mfma_f32_16x16x32_bf16(ah, bh[ct][ks], acc[ct], 0, 0, 0);
        acc[ct] = __builtin_amdgcn_mfma_f32_16x16x32_bf16(ah, bl[ct][ks], acc[ct], 0, 0, 0);
        acc[ct] = __builtin_amdgcn_mfma_f32_16x16x32_bf16(al, bh[ct][ks], acc[ct], 0, 0, 0);
      }
    }
    __syncthreads();
  }

  // ---- epilogue: C layout col=ln, row=qd*4+i (validated convention) ----
#pragma unroll
  for (int ct = 0; ct < 2; ++ct)
#pragma unroll
    for (int i = 0; i < 4; ++i) {
      int row = r0 + w * 16 + qd * 4 + i;
      o[(size_t)row * R_ + ct * 16 + ln] = (unsigned short)f2bf(acc[ct][i] * osc);
    }
}

// ---------------------------------------------------------------------------
// Kernel 2: vT[b][d][key] = bf16(v[b][key][d]).  64x64 tiles via LDS.
// grid (N/64, D/64, B), 256 thr.  (validated in R3)
// ---------------------------------------------------------------------------
__global__ __launch_bounds__(256) void vT_kernel(
    const float* __restrict__ v, unsigned short* __restrict__ vT)
{
  __shared__ unsigned short tile[64][72];
  const int t = threadIdx.x;
  const int key0 = blockIdx.x * 64;
  const int d0 = blockIdx.y * 64;
  const int b = blockIdx.z;
  const float* vb = v + (size_t)b * N_ * D_;

#pragma unroll
  for (int i = 0; i < 4; ++i) {
    int kl = (t >> 4) + 16 * i;
    int dl = (t & 15) * 4;
    float4 f = *(const float4*)&vb[(size_t)(key0 + kl) * D_ + d0 + dl];
    tile[dl + 0][kl] = (unsigned short)f2bf(f.x);
    tile[dl + 1][kl] = (unsigned short)f2bf(f.y);
    tile[dl + 2][kl] = (unsigned short)f2bf(f.z);
    tile[dl + 3][kl] = (unsigned short)f2bf(f.w);
  }
  __syncthreads();
  unsigned short* ob = vT + (size_t)b * D_ * N_;
#pragma unroll
  for (int i = 0; i < 2; ++i) {
    int dl = (t >> 3) + 32 * i;
    int kc = (t & 7) * 8;
    *(short8*)&ob[(size_t)(d0 + dl) * N_ + key0 + kc] =
        *(const short8*)&tile[dl][kc];
  }
}

// ---------------------------------------------------------------------------
// Kernel 3 (fused flash): out[b, q0:+128, d0:+256] = softmax(u vp^T) @ V.
// Per 64-key tile: S via MFMA (u pre-scaled -> exp2), P packed bf16 -> LDS
// (C->A layout round-trip), PV via MFMA from LDS. l held in registers per
// block (each block spans all keys) -> no atomics. P never touches HBM.
// grid (B, D/256, N/128). This round: pack via v_cvt_pk_bf16_f32 (1 op vs ~7).
// ---------------------------------------------------------------------------
__global__ __launch_bounds__(256, 2) void fused_attn_kernel(
    const unsigned short* __restrict__ ub, const unsigned short* __restrict__ vpb,
    const unsigned short* __restrict__ vT, float* __restrict__ out)
{
  __shared__ __align__(16) unsigned short plds[128 * 72];  // [qrow][key], 18 KB
  __shared__ __align__(16) unsigned short vlds[256 * 72];  // [d][key],   36 KB
  __shared__ float l_lds[128];

  const int t = threadIdx.x;
  const int lane = t & 63;
  const int w = t >> 6;
  const int qd = lane >> 4;
  const int ln = lane & 15;

  const int b  = blockIdx.x;
  const int d0 = blockIdx.y * 256;
  const int q0 = blockIdx.z * 128;

  const unsigned short* uB  = ub  + (size_t)b * N_ * R_;
  const unsigned short* vpB = vpb + (size_t)b * N_ * R_;
  const unsigned short* vTb = vT  + (size_t)b * D_ * N_;

  // u A-frags (S-phase): wave w covers S-rows 32w..32w+31 (rg2 = 0..1), K=R=32
  short8 ufrag[2];
#pragma unroll
  for (int rg2 = 0; rg2 < 2; ++rg2)
    ufrag[rg2] = *(const short8*)
        &uB[(size_t)(q0 + 32 * w + rg2 * 16 + ln) * R_ + qd * 8];

  f32x4 acc[4][8];
#pragma unroll
  for (int rg = 0; rg < 4; ++rg)
#pragma unroll
    for (int ct = 0; ct < 8; ++ct)
#pragma unroll
      for (int i = 0; i < 4; ++i) acc[rg][ct][i] = 0.f;

  float l_acc[2][4];
#pragma unroll
  for (int i = 0; i < 2; ++i)
#pragma unroll
    for (int j = 0; j < 4; ++j) l_acc[i][j] = 0.f;

  for (int k0 = 0; k0 < N_; k0 += 64) {
    // ---- stage V tile: 256 d x 64 k bf16, [d][key] stride 72 ----
#pragma unroll
    for (int i = 0; i < 8; ++i) {
      int idx = t + 256 * i;
      int dr = idx >> 3;
      int kc = idx & 7;
      *(short8*)&vlds[dr * 72 + kc * 8] =
          *(const short8*)&vTb[(size_t)(d0 + dr) * N_ + k0 + kc * 8];
    }

    // ---- S phase: wave computes rows 32w..+32 x keys k0..k0+64 ----
    short8 vpfrag[4];
#pragma unroll
    for (int ct2 = 0; ct2 < 4; ++ct2)
      vpfrag[ct2] = *(const short8*)
          &vpB[(size_t)(k0 + ct2 * 16 + ln) * R_ + qd * 8];

    f32x4 sacc[2][4];
#pragma unroll
    for (int rg2 = 0; rg2 < 2; ++rg2)
#pragma unroll
      for (int ct2 = 0; ct2 < 4; ++ct2) {
#pragma unroll
        for (int i = 0; i < 4; ++i) sacc[rg2][ct2][i] = 0.f;
        sacc[rg2][ct2] = __builtin_amdgcn_mfma_f32_16x16x32_bf16(
            ufrag[rg2], vpfrag[ct2], sacc[rg2][ct2], 0, 0, 0);
      }

    // exp2, l-accumulate, pack pairs (DPP + cvt_pk), write P to LDS
#pragma unroll
    for (int rg2 = 0; rg2 < 2; ++rg2) {
#pragma unroll
      for (int ct2 = 0; ct2 < 4; ++ct2) {
#pragma unroll
        for (int r = 0; r < 4; ++r) {
          float p = exp2f(sacc[rg2][ct2][r]);
          l_acc[rg2][r] += p;
          float pq = dpp_swap1(p);
          if ((ln & 1) == 0) {
            unsigned int pk = cvt_pk_bf16(p, pq);
            int row = 32 * w + rg2 * 16 + qd * 4 + r;
            *(unsigned int*)&plds[row * 72 + ct2 * 16 + (ln & 14)] = pk;
          }
        }
      }
    }
    __syncthreads();

    // ---- PV phase: rows (w>>1)*64..+64, d-cols (w&1)*128..+128 ----
#pragma unroll
    for (int s = 0; s < 2; ++s) {
      short8 bfr[8];
#pragma unroll
      for (int ct = 0; ct < 8; ++ct)
        bfr[ct] = *(const short8*)
            &vlds[((w & 1) * 128 + ct * 16 + ln) * 72 + s * 32 + qd * 8];
      short8 afr[4];
#pragma unroll
      for (int rg = 0; rg < 4; ++rg)
        afr[rg] = *(const short8*)
            &plds[((w >> 1) * 64 + rg * 16 + ln) * 72 + s * 32 + qd * 8];
#pragma unroll
      for (int rg = 0; rg < 4; ++rg)
#pragma unroll
        for (int ct = 0; ct < 8; ++ct)
          acc[rg][ct] = __builtin_amdgcn_mfma_f32_16x16x32_bf16(
              afr[rg], bfr[ct], acc[rg][ct], 0, 0, 0);
    }
    __syncthreads();
  }

  // ---- l: reduce over the 16 lanes of each quad-row group ----
#pragma unroll
  for (int rg2 = 0; rg2 < 2; ++rg2) {
#pragma unroll
    for (int r = 0; r < 4; ++r) {
      float v = l_acc[rg2][r];
      v += __shfl_xor(v, 1);
      v += __shfl_xor(v, 2);
      v += __shfl_xor(v, 4);
      v += __shfl_xor(v, 8);
      if (ln == 0) l_lds[32 * w + rg2 * 16 + qd * 4 + r] = v;
    }
  }
  __syncthreads();

  // ---- epilogue: out = acc / l ----
#pragma unroll
  for (int rg = 0; rg < 4; ++rg) {
#pragma unroll
    for (int r = 0; r < 4; ++r) {
      const int row = (w >> 1) * 64 + rg * 16 + qd * 4 + r;
      const float inv = 1.0f / l_lds[row];
      float* orow = out + ((size_t)b * N_ + q0 + row) * D_ + d0 + (w & 1) * 128;
#pragma unroll
      for (int ct = 0; ct < 8; ++ct)
        orow[ct * 16 + ln] = acc[rg][ct][r] * inv;
    }
  }
}

// ---------------------------------------------------------------------------
// Fallback (R1, known-good fp32 fused) — used only if ws too small.
// ---------------------------------------------------------------------------
__global__ __launch_bounds__(256) void uv_gemm_f32(
    const float* __restrict__ q, const float* __restrict__ kmat,
    const float* __restrict__ Wu, const float* __restrict__ Wv,
    float* __restrict__ u, float* __restrict__ vp)
{
  __shared__ float x_lds[64][68];
  __shared__ float w_lds[64][36];
  const int t = threadIdx.x;
  const float* __restrict__ x = (blockIdx.y == 0) ? q : kmat;
  const float* __restrict__ W = (blockIdx.y == 0) ? Wu : Wv;
  float* __restrict__ o = (blockIdx.y == 0) ? u : vp;
  const int m0 = blockIdx.x * 64;
  const int row = t >> 2;
  const int c0 = (t & 3) * 8;
  float acc[8];
#pragma unroll
  for (int i = 0; i < 8; ++i) acc[i] = 0.f;
  for (int k0 = 0; k0 < D_; k0 += 64) {
#pragma unroll
    for (int i = 0; i < 4; ++i) {
      int f4 = t + i * 256;
      int r_ = f4 >> 4, cc = (f4 & 15) * 4;
      *(float4*)&x_lds[r_][cc] = *(const float4*)&x[(size_t)(m0 + r_) * D_ + k0 + cc];
    }
#pragma unroll
    for (int i = 0; i < 2; ++i) {
      int f4 = t + i * 256;
      int r_ = f4 >> 3, cc = (f4 & 7) * 4;
      *(float4*)&w_lds[r_][cc] = *(const float4*)&W[(size_t)(k0 + r_) * R_ + cc];
    }
    __syncthreads();
#pragma unroll 8
    for (int kk = 0; kk < 64; ++kk) {
      float a = x_lds[row][kk];
      float4 b0 = *(float4*)&w_lds[kk][c0];
      float4 b1 = *(float4*)&w_lds[kk][c0 + 4];
      acc[0] = fmaf(a, b0.x, acc[0]); acc[1] = fmaf(a, b0.y, acc[1]);
      acc[2] = fmaf(a, b0.z, acc[2]); acc[3] = fmaf(a, b0.w, acc[3]);
      acc[4] = fmaf(a, b1.x, acc[4]); acc[5] = fmaf(a, b1.y, acc[5]);
      acc[6] = fmaf(a, b1.z, acc[6]); acc[7] = fmaf(a, b1.w, acc[7]);
    }
    __syncthreads();
  }
  *(float4*)&o[(size_t)(m0 + row) * R_ + c0] = make_float4(acc[0], acc[1], acc[2], acc[3]);
  *(float4*)&o[(size_t)(m0 + row) * R_ + c0 + 4] = make_float4(acc[4], acc[5], acc[6], acc[7]);
}

__global__ __launch_bounds__(256) void attn_kernel(
    const float* __restrict__ u, const float* __restrict__ vp,
    const float* __restrict__ v, float* __restrict__ out)
{
  __shared__ float u_lds[64][36];
  __shared__ float vpT_lds[32][36];
  __shared__ float p_lds[64][36];
  __shared__ float v_lds[32][132];
  __shared__ float l_lds[64];
  const int t = threadIdx.x;
  const int b = blockIdx.z;
  const int m0 = blockIdx.x * 64;
  const int d0 = blockIdx.y * 128;
  const size_t rb = (size_t)b * N_;
#pragma unroll
  for (int i = 0; i < 2; ++i) {
    int f4 = t + i * 256;
    int r_ = f4 >> 3, cc = (f4 & 7) * 4;
    *(float4*)&u_lds[r_][cc] = *(const float4*)&u[(rb + m0 + r_) * R_ + cc];
  }
  const int srow = t >> 2;
  const int kc0 = (t & 3) * 8;
  const int rg = t >> 5;
  const int cx = t & 31;
  float acc[8][4];
#pragma unroll
  for (int i = 0; i < 8; ++i)
#pragma unroll
    for (int j = 0; j < 4; ++j) acc[i][j] = 0.f;
  float l_part = 0.f;
  const float scale = 0.17677669529663687f;
  for (int k0 = 0; k0 < N_; k0 += 32) {
    {
      int r_ = t >> 3, cc = (t & 7) * 4;
      float4 w4 = *(const float4*)&vp[(rb + k0 + r_) * R_ + cc];
      vpT_lds[cc + 0][r_] = w4.x; vpT_lds[cc + 1][r_] = w4.y;
      vpT_lds[cc + 2][r_] = w4.z; vpT_lds[cc + 3][r_] = w4.w;
    }
#pragma unroll
    for (int i = 0; i < 4; ++i) {
      int f4 = t + i * 256;
      int r_ = f4 >> 5, cc = (f4 & 31) * 4;
      *(float4*)&v_lds[r_][cc] = *(const float4*)&v[(rb + k0 + r_) * D_ + d0 + cc];
    }
    __syncthreads();
    float s[8];
#pragma unroll
    for (int j = 0; j < 8; ++j) s[j] = 0.f;
#pragma unroll
    for (int rr = 0; rr < 32; rr += 4) {
      float4 u4 = *(float4*)&u_lds[srow][rr];
      float ua[4] = {u4.x, u4.y, u4.z, u4.w};
#pragma unroll
      for (int q4 = 0; q4 < 4; ++q4) {
        float uu = ua[q4];
        float4 g0 = *(float4*)&vpT_lds[rr + q4][kc0];
        float4 g1 = *(float4*)&vpT_lds[rr + q4][kc0 + 4];
        s[0] = fmaf(uu, g0.x, s[0]); s[1] = fmaf(uu, g0.y, s[1]);
        s[2] = fmaf(uu, g0.z, s[2]); s[3] = fmaf(uu, g0.w, s[3]);
        s[4] = fmaf(uu, g1.x, s[4]); s[5] = fmaf(uu, g1.y, s[5]);
        s[6] = fmaf(uu, g1.z, s[6]); s[7] = fmaf(uu, g1.w, s[7]);
      }
    }
    float p[8];
    float lsum = 0.f;
#pragma unroll
    for (int j = 0; j < 8; ++j) { p[j] = __expf(s[j] * scale); lsum += p[j]; }
    l_part += lsum;
    *(float4*)&p_lds[srow][kc0] = make_float4(p[0], p[1], p[2], p[3]);
    *(float4*)&p_lds[srow][kc0 + 4] = make_float4(p[4], p[5], p[6], p[7]);
    __syncthreads();
#pragma unroll 4
    for (int kk = 0; kk < 32; ++kk) {
      float4 bv = *(float4*)&v_lds[kk][cx * 4];
#pragma unroll
      for (int i = 0; i < 8; ++i) {
        float a = p_lds[rg * 8 + i][kk];
        acc[i][0] = fmaf(a, bv.x, acc[i][0]); acc[i][1] = fmaf(a, bv.y, acc[i][1]);
        acc[i][2] = fmaf(a, bv.z, acc[i][2]); acc[i][3] = fmaf(a, bv.w, acc[i][3]);
      }
    }
    __syncthreads();
  }
  l_part += __shfl_xor(l_part, 1);
  l_part += __shfl_xor(l_part, 2);
  if ((t & 3) == 0) l_lds[srow] = l_part;
  __syncthreads();
#pragma unroll
  for (int i = 0; i < 8; ++i) {
    int row = rg * 8 + i;
    float inv = 1.0f / l_lds[row];
    *(float4*)&out[(rb + m0 + row) * D_ + d0 + cx * 4] =
        make_float4(acc[i][0] * inv, acc[i][1] * inv, acc[i][2] * inv, acc[i][3] * inv);
  }
}

// ---------------------------------------------------------------------------
extern "C" void kernel_launch(void* const* d_in, const int* in_sizes, int n_in,
                              void* d_out, int out_size, void* d_ws, size_t ws_size,
                              hipStream_t stream) {
  const float* q  = (const float*)d_in[0];
  const float* k  = (const float*)d_in[1];
  const float* v  = (const float*)d_in[2];
  const float* Wu = (const float*)d_in[3];
  const float* Wv = (const float*)d_in[4];
  float* out = (float*)d_out;

  // ws layout: u_bf 1MB | vp_bf 1MB | vT 32MiB  (~35.6 MB total)
  const size_t o_u  = 0;
  const size_t o_vp = (size_t)1 << 20;
  const size_t o_vt = (size_t)2 << 20;
  const size_t vt_bytes = (size_t)B_ * D_ * N_ * 2;
  const size_t need = o_vt + vt_bytes;

  if (ws_size >= need) {
    unsigned short* ub  = (unsigned short*)((char*)d_ws + o_u);
    unsigned short* vpb = (unsigned short*)((char*)d_ws + o_vp);
    unsigned short* vtb = (unsigned short*)((char*)d_ws + o_vt);

    uv_mfma_kernel<<<dim3(BN_ / 64, 2), 256, 0, stream>>>(q, k, Wu, Wv, ub, vpb);
    vT_kernel<<<dim3(N_ / 64, D_ / 64, B_), 256, 0, stream>>>(v, vtb);
    fused_attn_kernel<<<dim3(B_, D_ / 256, N_ / 128), 256, 0, stream>>>(
        ub, vpb, vtb, out);
  } else {
    float* uf  = (float*)d_ws;
    float* vpf = uf + (size_t)BN_ * R_;
    uv_gemm_f32<<<dim3(BN_ / 64, 2), 256, 0, stream>>>(q, k, Wu, Wv, uf, vpf);
    attn_kernel<<<dim3(N_ / 64, D_ / 128, B_), 256, 0, stream>>>(uf, vpf, v, out);
  }
}

// Round 2
// 403.840 us; speedup vs baseline: 1.2397x; 1.0749x over previous
//
#include <hip/hip_runtime.h>

#define B_ 4
#define N_ 4096
#define D_ 1024
#define R_ 32
#define BN_ (B_ * N_)

typedef __attribute__((ext_vector_type(8))) short short8;
typedef __attribute__((ext_vector_type(4))) float f32x4;

// round-to-nearest-even fp32 -> bf16
__device__ inline unsigned int f2bf(float f) {
  unsigned int u = __float_as_uint(f);
  return (u + 0x7fffu + ((u >> 16) & 1u)) >> 16;
}

// packed RNE fp32x2 -> bf16x2 in one VALU op (no builtin on gfx950; T12 recipe)
__device__ inline unsigned int cvt_pk_bf16(float lo, float hi) {
  unsigned int r;
  asm("v_cvt_pk_bf16_f32 %0, %1, %2" : "=v"(r) : "v"(lo), "v"(hi));
  return r;
}

// swap lanes 0<->1, 2<->3 (pairs ln^1) on the VALU pipe (DPP quad_perm [1,0,3,2])
__device__ inline float dpp_swap1(float x) {
  return __int_as_float(
      __builtin_amdgcn_mov_dpp(__float_as_int(x), 0xB1, 0xF, 0xF, true));
}

// ---------------------------------------------------------------------------
// Kernel 1: u = (q @ Wu) * log2e/sqrt(R), vp = k @ Wv via split-bf16 MFMA.
//   x = xh + xl (two RNE bf16 halves), W likewise; u = xh*Wh + xh*Wl + xl*Wh
// HBM-bound (~134 MB reads).  grid (BN/64, 2), 256 thr.
// ---------------------------------------------------------------------------
#define UV_GS 136
#define UV_RS 552   // 4*UV_GS + 8

__global__ __launch_bounds__(256) void uv_mfma_kernel(
    const float* __restrict__ q, const float* __restrict__ kmat,
    const float* __restrict__ Wu, const float* __restrict__ Wv,
    unsigned short* __restrict__ u, unsigned short* __restrict__ vp)
{
  __shared__ unsigned short ah_lds[8 * UV_RS];   // hi A-frags, 8 regions
  __shared__ unsigned short al_lds[8 * UV_RS];   // lo A-frags
  __shared__ unsigned short wth[32][72];         // W^T hi  [col][k], pad 8
  __shared__ unsigned short wtl[32][72];         // W^T lo

  const int t = threadIdx.x;
  const float* __restrict__ x = (blockIdx.y == 0) ? q : kmat;
  const float* __restrict__ W = (blockIdx.y == 0) ? Wu : Wv;
  unsigned short* __restrict__ o = (blockIdx.y == 0) ? u : vp;
  // 1/sqrt(32) * log2(e): fold softmax scale + exp->exp2 conversion into u
  const float osc = (blockIdx.y == 0)
      ? (0.17677669529663687f * 1.4426950408889634f) : 1.0f;

  const int r0 = blockIdx.x * 64;
  const int lane = t & 63;
  const int w = t >> 6;        // wave id == rowtile rt
  const int qd = lane >> 4;
  const int ln = lane & 15;

  f32x4 acc[2];
#pragma unroll
  for (int ct = 0; ct < 2; ++ct)
#pragma unroll
    for (int i = 0; i < 4; ++i) acc[ct][i] = 0.f;

  const int a_rd = qd * UV_GS + ln * 8;  // per-lane offset inside a region

  for (int k0 = 0; k0 < D_; k0 += 64) {
    // ---- stage x tile (64 rows x 64 k f32), split to bf16 hi/lo A-frags ----
#pragma unroll
    for (int i = 0; i < 4; ++i) {
      int idx = t + i * 256;          // 0..1023
      int row = idx >> 4;             // 0..63
      int kc = (idx & 15) * 4;        // 0..60
      float4 f = *(const float4*)&x[(size_t)(r0 + row) * D_ + k0 + kc];
      int fr = (row >> 4) * 2 + (kc >> 5);
      int off = fr * UV_RS + ((kc >> 3) & 3) * UV_GS + (row & 15) * 8 + (kc & 7);
      unsigned int h01 = cvt_pk_bf16(f.x, f.y);
      unsigned int h23 = cvt_pk_bf16(f.z, f.w);
      float hx = __uint_as_float(h01 << 16);
      float hy = __uint_as_float(h01 & 0xffff0000u);
      float hz = __uint_as_float(h23 << 16);
      float hw = __uint_as_float(h23 & 0xffff0000u);
      unsigned int l01 = cvt_pk_bf16(f.x - hx, f.y - hy);
      unsigned int l23 = cvt_pk_bf16(f.z - hz, f.w - hw);
      *(unsigned int*)&ah_lds[off]     = h01;
      *(unsigned int*)&ah_lds[off + 2] = h23;
      *(unsigned int*)&al_lds[off]     = l01;
      *(unsigned int*)&al_lds[off + 2] = l23;
    }
    // ---- stage W chunk transposed: [k][32] f32 -> W^T hi/lo [col][k] bf16 ----
#pragma unroll
    for (int i = 0; i < 2; ++i) {
      int idx = t + i * 256;          // 0..511
      int kr = idx >> 3;              // 0..63
      int cc = (idx & 7) * 4;         // 0..28
      float4 fw = *(const float4*)&W[(size_t)(k0 + kr) * R_ + cc];
      float vv[4] = {fw.x, fw.y, fw.z, fw.w};
#pragma unroll
      for (int j = 0; j < 4; ++j) {
        unsigned int hb = f2bf(vv[j]);
        wth[cc + j][kr] = (unsigned short)hb;
        float lo = vv[j] - __uint_as_float(hb << 16);
        wtl[cc + j][kr] = (unsigned short)f2bf(lo);
      }
    }
    __syncthreads();

    // ---- B-frags (tiny W) to registers for this k-tile ----
    short8 bh[2][2], bl[2][2];        // [coltile][kstep]
#pragma unroll
    for (int ct = 0; ct < 2; ++ct)
#pragma unroll
      for (int ks = 0; ks < 2; ++ks) {
        bh[ct][ks] = *(const short8*)&wth[ct * 16 + ln][ks * 32 + qd * 8];
        bl[ct][ks] = *(const short8*)&wtl[ct * 16 + ln][ks * 32 + qd * 8];
      }

    // ---- MFMA: 2 ksteps x 2 coltiles x 3 split terms ----
#pragma unroll
    for (int ks = 0; ks < 2; ++ks) {
      short8 ah = *(const short8*)&ah_lds[(w * 2 + ks) * UV_RS + a_rd];
      short8 al = *(const short8*)&al_lds[(w * 2 + ks) * UV_RS + a_rd];
#pragma unroll
      for (int ct = 0; ct < 2; ++ct) {
        acc[ct] = __builtin_amdgcn_mfma_f32_16x16x32_bf16(ah, bh[ct][ks], acc[ct], 0, 0, 0);
        acc[ct] = __builtin_amdgcn_mfma_f32_16x16x32_bf16(ah, bl[ct][ks], acc[ct], 0, 0, 0);
        acc[ct] = __builtin_amdgcn_mfma_f32_16x16x32_bf16(al, bh[ct][ks], acc[ct], 0, 0, 0);
      }
    }
    __syncthreads();
  }

  // ---- epilogue: C layout col=ln, row=qd*4+i (validated convention) ----
#pragma unroll
  for (int ct = 0; ct < 2; ++ct)
#pragma unroll
    for (int i = 0; i < 4; ++i) {
      int row = r0 + w * 16 + qd * 4 + i;
      o[(size_t)row * R_ + ct * 16 + ln] = (unsigned short)f2bf(acc[ct][i] * osc);
    }
}

// ---------------------------------------------------------------------------
// Kernel 2: vT[b][d][key] = bf16(v[b][key][d]).  64x64 tiles via LDS.
// grid (N/64, D/64, B), 256 thr.  (validated in R3)
// ---------------------------------------------------------------------------
__global__ __launch_bounds__(256) void vT_kernel(
    const float* __restrict__ v, unsigned short* __restrict__ vT)
{
  __shared__ unsigned short tile[64][72];
  const int t = threadIdx.x;
  const int key0 = blockIdx.x * 64;
  const int d0 = blockIdx.y * 64;
  const int b = blockIdx.z;
  const float* vb = v + (size_t)b * N_ * D_;

#pragma unroll
  for (int i = 0; i < 4; ++i) {
    int kl = (t >> 4) + 16 * i;
    int dl = (t & 15) * 4;
    float4 f = *(const float4*)&vb[(size_t)(key0 + kl) * D_ + d0 + dl];
    tile[dl + 0][kl] = (unsigned short)f2bf(f.x);
    tile[dl + 1][kl] = (unsigned short)f2bf(f.y);
    tile[dl + 2][kl] = (unsigned short)f2bf(f.z);
    tile[dl + 3][kl] = (unsigned short)f2bf(f.w);
  }
  __syncthreads();
  unsigned short* ob = vT + (size_t)b * D_ * N_;
#pragma unroll
  for (int i = 0; i < 2; ++i) {
    int dl = (t >> 3) + 32 * i;
    int kc = (t & 7) * 8;
    *(short8*)&ob[(size_t)(d0 + dl) * N_ + key0 + kc] =
        *(const short8*)&tile[dl][kc];
  }
}

// ---------------------------------------------------------------------------
// Kernel 3 (fused flash): out[b, q0:+128, d0:+256] = softmax(u vp^T) @ V.
// This round: vlds ELIMINATED. PV B-frags (V columns) are prefetched at the
// top of each k-tile directly from L2-resident vT into registers (T14: issue
// early, consume after the barrier -> S-phase hides the L2 latency). Waves
// own disjoint 64-wide d-slices across all 128 q-rows (zero B-frag
// redundancy: 1.07 GB total L2 traffic ~ 0.9 TB/s per XCD).
// LDS now holds only P (18.4 KB). grid (B, D/256, N/128).
// ---------------------------------------------------------------------------
__global__ __launch_bounds__(256, 2) void fused_attn_kernel(
    const unsigned short* __restrict__ ub, const unsigned short* __restrict__ vpb,
    const unsigned short* __restrict__ vT, float* __restrict__ out)
{
  __shared__ __align__(16) unsigned short plds[128 * 72];  // [qrow][key], 18 KB
  __shared__ float l_lds[128];

  const int t = threadIdx.x;
  const int lane = t & 63;
  const int w = t >> 6;
  const int qd = lane >> 4;
  const int ln = lane & 15;

  const int b  = blockIdx.x;
  const int d0 = blockIdx.y * 256;
  const int q0 = blockIdx.z * 128;

  const unsigned short* uB  = ub  + (size_t)b * N_ * R_;
  const unsigned short* vpB = vpb + (size_t)b * N_ * R_;
  const unsigned short* vTb = vT  + (size_t)b * D_ * N_;

  // u A-frags (S-phase): wave w covers S-rows 32w..32w+31 (rg2 = 0..1), K=R=32
  short8 ufrag[2];
#pragma unroll
  for (int rg2 = 0; rg2 < 2; ++rg2)
    ufrag[rg2] = *(const short8*)
        &uB[(size_t)(q0 + 32 * w + rg2 * 16 + ln) * R_ + qd * 8];

  // PV: wave w owns d-cols d0 + 64w .. +64 (ct=0..3), all 128 q-rows (rg=0..7)
  const unsigned short* vTw = vTb + (size_t)(d0 + w * 64) * N_;

  f32x4 acc[8][4];
#pragma unroll
  for (int rg = 0; rg < 8; ++rg)
#pragma unroll
    for (int ct = 0; ct < 4; ++ct)
#pragma unroll
      for (int i = 0; i < 4; ++i) acc[rg][ct][i] = 0.f;

  float l_acc[2][4];
#pragma unroll
  for (int i = 0; i < 2; ++i)
#pragma unroll
    for (int j = 0; j < 4; ++j) l_acc[i][j] = 0.f;

  for (int k0 = 0; k0 < N_; k0 += 64) {
    // ---- prefetch PV B-frags for this k-tile straight from L2 (no LDS) ----
    short8 bfr[4][2];
#pragma unroll
    for (int ct = 0; ct < 4; ++ct)
#pragma unroll
      for (int s = 0; s < 2; ++s)
        bfr[ct][s] = *(const short8*)
            &vTw[(size_t)(ct * 16 + ln) * N_ + k0 + s * 32 + qd * 8];

    // ---- S phase: wave computes rows 32w..+32 x keys k0..k0+64 ----
    short8 vpfrag[4];
#pragma unroll
    for (int ct2 = 0; ct2 < 4; ++ct2)
      vpfrag[ct2] = *(const short8*)
          &vpB[(size_t)(k0 + ct2 * 16 + ln) * R_ + qd * 8];

    f32x4 sacc[2][4];
#pragma unroll
    for (int rg2 = 0; rg2 < 2; ++rg2)
#pragma unroll
      for (int ct2 = 0; ct2 < 4; ++ct2) {
#pragma unroll
        for (int i = 0; i < 4; ++i) sacc[rg2][ct2][i] = 0.f;
        sacc[rg2][ct2] = __builtin_amdgcn_mfma_f32_16x16x32_bf16(
            ufrag[rg2], vpfrag[ct2], sacc[rg2][ct2], 0, 0, 0);
      }

    // exp2, l-accumulate, pack pairs (DPP + cvt_pk), write P to LDS
#pragma unroll
    for (int rg2 = 0; rg2 < 2; ++rg2) {
#pragma unroll
      for (int ct2 = 0; ct2 < 4; ++ct2) {
#pragma unroll
        for (int r = 0; r < 4; ++r) {
          float p = exp2f(sacc[rg2][ct2][r]);
          l_acc[rg2][r] += p;
          float pq = dpp_swap1(p);
          if ((ln & 1) == 0) {
            unsigned int pk = cvt_pk_bf16(p, pq);
            int row = 32 * w + rg2 * 16 + qd * 4 + r;
            *(unsigned int*)&plds[row * 72 + ct2 * 16 + (ln & 14)] = pk;
          }
        }
      }
    }
    __syncthreads();

    // ---- PV phase: all 128 q-rows x this wave's 64 d-cols ----
    __builtin_amdgcn_s_setprio(1);
#pragma unroll
    for (int s = 0; s < 2; ++s) {
      short8 afr[8];
#pragma unroll
      for (int rg = 0; rg < 8; ++rg)
        afr[rg] = *(const short8*)
            &plds[(rg * 16 + ln) * 72 + s * 32 + qd * 8];
#pragma unroll
      for (int rg = 0; rg < 8; ++rg)
#pragma unroll
        for (int ct = 0; ct < 4; ++ct)
          acc[rg][ct] = __builtin_amdgcn_mfma_f32_16x16x32_bf16(
              afr[rg], bfr[ct][s], acc[rg][ct], 0, 0, 0);
    }
    __builtin_amdgcn_s_setprio(0);
    __syncthreads();
  }

  // ---- l: reduce over the 16 lanes of each quad-row group ----
#pragma unroll
  for (int rg2 = 0; rg2 < 2; ++rg2) {
#pragma unroll
    for (int r = 0; r < 4; ++r) {
      float v = l_acc[rg2][r];
      v += __shfl_xor(v, 1);
      v += __shfl_xor(v, 2);
      v += __shfl_xor(v, 4);
      v += __shfl_xor(v, 8);
      if (ln == 0) l_lds[32 * w + rg2 * 16 + qd * 4 + r] = v;
    }
  }
  __syncthreads();

  // ---- epilogue: out = acc / l ----
#pragma unroll
  for (int rg = 0; rg < 8; ++rg) {
#pragma unroll
    for (int r = 0; r < 4; ++r) {
      const int row = rg * 16 + qd * 4 + r;
      const float inv = 1.0f / l_lds[row];
      float* orow = out + ((size_t)b * N_ + q0 + row) * D_ + d0 + w * 64;
#pragma unroll
      for (int ct = 0; ct < 4; ++ct)
        orow[ct * 16 + ln] = acc[rg][ct][r] * inv;
    }
  }
}

// ---------------------------------------------------------------------------
// Fallback (R1, known-good fp32 fused) — used only if ws too small.
// ---------------------------------------------------------------------------
__global__ __launch_bounds__(256) void uv_gemm_f32(
    const float* __restrict__ q, const float* __restrict__ kmat,
    const float* __restrict__ Wu, const float* __restrict__ Wv,
    float* __restrict__ u, float* __restrict__ vp)
{
  __shared__ float x_lds[64][68];
  __shared__ float w_lds[64][36];
  const int t = threadIdx.x;
  const float* __restrict__ x = (blockIdx.y == 0) ? q : kmat;
  const float* __restrict__ W = (blockIdx.y == 0) ? Wu : Wv;
  float* __restrict__ o = (blockIdx.y == 0) ? u : vp;
  const int m0 = blockIdx.x * 64;
  const int row = t >> 2;
  const int c0 = (t & 3) * 8;
  float acc[8];
#pragma unroll
  for (int i = 0; i < 8; ++i) acc[i] = 0.f;
  for (int k0 = 0; k0 < D_; k0 += 64) {
#pragma unroll
    for (int i = 0; i < 4; ++i) {
      int f4 = t + i * 256;
      int r_ = f4 >> 4, cc = (f4 & 15) * 4;
      *(float4*)&x_lds[r_][cc] = *(const float4*)&x[(size_t)(m0 + r_) * D_ + k0 + cc];
    }
#pragma unroll
    for (int i = 0; i < 2; ++i) {
      int f4 = t + i * 256;
      int r_ = f4 >> 3, cc = (f4 & 7) * 4;
      *(float4*)&w_lds[r_][cc] = *(const float4*)&W[(size_t)(k0 + r_) * R_ + cc];
    }
    __syncthreads();
#pragma unroll 8
    for (int kk = 0; kk < 64; ++kk) {
      float a = x_lds[row][kk];
      float4 b0 = *(float4*)&w_lds[kk][c0];
      float4 b1 = *(float4*)&w_lds[kk][c0 + 4];
      acc[0] = fmaf(a, b0.x, acc[0]); acc[1] = fmaf(a, b0.y, acc[1]);
      acc[2] = fmaf(a, b0.z, acc[2]); acc[3] = fmaf(a, b0.w, acc[3]);
      acc[4] = fmaf(a, b1.x, acc[4]); acc[5] = fmaf(a, b1.y, acc[5]);
      acc[6] = fmaf(a, b1.z, acc[6]); acc[7] = fmaf(a, b1.w, acc[7]);
    }
    __syncthreads();
  }
  *(float4*)&o[(size_t)(m0 + row) * R_ + c0] = make_float4(acc[0], acc[1], acc[2], acc[3]);
  *(float4*)&o[(size_t)(m0 + row) * R_ + c0 + 4] = make_float4(acc[4], acc[5], acc[6], acc[7]);
}

__global__ __launch_bounds__(256) void attn_kernel(
    const float* __restrict__ u, const float* __restrict__ vp,
    const float* __restrict__ v, float* __restrict__ out)
{
  __shared__ float u_lds[64][36];
  __shared__ float vpT_lds[32][36];
  __shared__ float p_lds[64][36];
  __shared__ float v_lds[32][132];
  __shared__ float l_lds[64];
  const int t = threadIdx.x;
  const int b = blockIdx.z;
  const int m0 = blockIdx.x * 64;
  const int d0 = blockIdx.y * 128;
  const size_t rb = (size_t)b * N_;
#pragma unroll
  for (int i = 0; i < 2; ++i) {
    int f4 = t + i * 256;
    int r_ = f4 >> 3, cc = (f4 & 7) * 4;
    *(float4*)&u_lds[r_][cc] = *(const float4*)&u[(rb + m0 + r_) * R_ + cc];
  }
  const int srow = t >> 2;
  const int kc0 = (t & 3) * 8;
  const int rg = t >> 5;
  const int cx = t & 31;
  float acc[8][4];
#pragma unroll
  for (int i = 0; i < 8; ++i)
#pragma unroll
    for (int j = 0; j < 4; ++j) acc[i][j] = 0.f;
  float l_part = 0.f;
  const float scale = 0.17677669529663687f;
  for (int k0 = 0; k0 < N_; k0 += 32) {
    {
      int r_ = t >> 3, cc = (t & 7) * 4;
      float4 w4 = *(const float4*)&vp[(rb + k0 + r_) * R_ + cc];
      vpT_lds[cc + 0][r_] = w4.x; vpT_lds[cc + 1][r_] = w4.y;
      vpT_lds[cc + 2][r_] = w4.z; vpT_lds[cc + 3][r_] = w4.w;
    }
#pragma unroll
    for (int i = 0; i < 4; ++i) {
      int f4 = t + i * 256;
      int r_ = f4 >> 5, cc = (f4 & 31) * 4;
      *(float4*)&v_lds[r_][cc] = *(const float4*)&v[(rb + k0 + r_) * D_ + d0 + cc];
    }
    __syncthreads();
    float s[8];
#pragma unroll
    for (int j = 0; j < 8; ++j) s[j] = 0.f;
#pragma unroll
    for (int rr = 0; rr < 32; rr += 4) {
      float4 u4 = *(float4*)&u_lds[srow][rr];
      float ua[4] = {u4.x, u4.y, u4.z, u4.w};
#pragma unroll
      for (int q4 = 0; q4 < 4; ++q4) {
        float uu = ua[q4];
        float4 g0 = *(float4*)&vpT_lds[rr + q4][kc0];
        float4 g1 = *(float4*)&vpT_lds[rr + q4][kc0 + 4];
        s[0] = fmaf(uu, g0.x, s[0]); s[1] = fmaf(uu, g0.y, s[1]);
        s[2] = fmaf(uu, g0.z, s[2]); s[3] = fmaf(uu, g0.w, s[3]);
        s[4] = fmaf(uu, g1.x, s[4]); s[5] = fmaf(uu, g1.y, s[5]);
        s[6] = fmaf(uu, g1.z, s[6]); s[7] = fmaf(uu, g1.w, s[7]);
      }
    }
    float p[8];
    float lsum = 0.f;
#pragma unroll
    for (int j = 0; j < 8; ++j) { p[j] = __expf(s[j] * scale); lsum += p[j]; }
    l_part += lsum;
    *(float4*)&p_lds[srow][kc0] = make_float4(p[0], p[1], p[2], p[3]);
    *(float4*)&p_lds[srow][kc0 + 4] = make_float4(p[4], p[5], p[6], p[7]);
    __syncthreads();
#pragma unroll 4
    for (int kk = 0; kk < 32; ++kk) {
      float4 bv = *(float4*)&v_lds[kk][cx * 4];
#pragma unroll
      for (int i = 0; i < 8; ++i) {
        float a = p_lds[rg * 8 + i][kk];
        acc[i][0] = fmaf(a, bv.x, acc[i][0]); acc[i][1] = fmaf(a, bv.y, acc[i][1]);
        acc[i][2] = fmaf(a, bv.z, acc[i][2]); acc[i][3] = fmaf(a, bv.w, acc[i][3]);
      }
    }
    __syncthreads();
  }
  l_part += __shfl_xor(l_part, 1);
  l_part += __shfl_xor(l_part, 2);
  if ((t & 3) == 0) l_lds[srow] = l_part;
  __syncthreads();
#pragma unroll
  for (int i = 0; i < 8; ++i) {
    int row = rg * 8 + i;
    float inv = 1.0f / l_lds[row];
    *(float4*)&out[(rb + m0 + row) * D_ + d0 + cx * 4] =
        make_float4(acc[i][0] * inv, acc[i][1] * inv, acc[i][2] * inv, acc[i][3] * inv);
  }
}

// ---------------------------------------------------------------------------
extern "C" void kernel_launch(void* const* d_in, const int* in_sizes, int n_in,
                              void* d_out, int out_size, void* d_ws, size_t ws_size,
                              hipStream_t stream) {
  const float* q  = (const float*)d_in[0];
  const float* k  = (const float*)d_in[1];
  const float* v  = (const float*)d_in[2];
  const float* Wu = (const float*)d_in[3];
  const float* Wv = (const float*)d_in[4];
  float* out = (float*)d_out;

  // ws layout: u_bf 1MB | vp_bf 1MB | vT 32MiB  (~35.6 MB total)
  const size_t o_u  = 0;
  const size_t o_vp = (size_t)1 << 20;
  const size_t o_vt = (size_t)2 << 20;
  const size_t vt_bytes = (size_t)B_ * D_ * N_ * 2;
  const size_t need = o_vt + vt_bytes;

  if (ws_size >= need) {
    unsigned short* ub  = (unsigned short*)((char*)d_ws + o_u);
    unsigned short* vpb = (unsigned short*)((char*)d_ws + o_vp);
    unsigned short* vtb = (unsigned short*)((char*)d_ws + o_vt);

    uv_mfma_kernel<<<dim3(BN_ / 64, 2), 256, 0, stream>>>(q, k, Wu, Wv, ub, vpb);
    vT_kernel<<<dim3(N_ / 64, D_ / 64, B_), 256, 0, stream>>>(v, vtb);
    fused_attn_kernel<<<dim3(B_, D_ / 256, N_ / 128), 256, 0, stream>>>(
        ub, vpb, vtb, out);
  } else {
    float* uf  = (float*)d_ws;
    float* vpf = uf + (size_t)BN_ * R_;
    uv_gemm_f32<<<dim3(BN_ / 64, 2), 256, 0, stream>>>(q, k, Wu, Wv, uf, vpf);
    attn_kernel<<<dim3(N_ / 64, D_ / 128, B_), 256, 0, stream>>>(uf, vpf, v, out);
  }
}